// Round 1
// baseline (721.411 us; speedup 1.0000x reference)
//
#include <hip/hip_runtime.h>
#include <hip/hip_bf16.h>
#include <math.h>

#define BB 8
#define SS 2048
#define DD 1024
#define HH 16
#define DHH 64
#define NROWS (BB*SS)   // 16384

typedef unsigned short u16;
typedef __attribute__((ext_vector_type(8))) __bf16 bf16x8;
typedef __attribute__((ext_vector_type(4))) float f32x4;

__device__ __forceinline__ u16 f2bf(float f) {
    union { float f; unsigned u; } v; v.f = f;
    unsigned r = v.u + 0x7fffu + ((v.u >> 16) & 1u);
    return (u16)(r >> 16);
}
__device__ __forceinline__ float bf2f(u16 b) {
    union { unsigned u; float f; } v; v.u = ((unsigned)b) << 16;
    return v.f;
}

__device__ __forceinline__ void load_lds16(const void* g, void* l) {
    __builtin_amdgcn_global_load_lds(
        (const __attribute__((address_space(1))) unsigned int*)g,
        (__attribute__((address_space(3))) unsigned int*)l,
        16, 0, 0);
}

// ---------------- cast hs fp32 -> bf16 ----------------
__global__ __launch_bounds__(256) void cast_bf16_kernel(const float* __restrict__ in,
                                                        u16* __restrict__ out, int n4) {
    int i = blockIdx.x * 256 + threadIdx.x;
    if (i >= n4) return;
    float4 v = ((const float4*)in)[i];
    ushort4 o;
    o.x = f2bf(v.x); o.y = f2bf(v.y); o.z = f2bf(v.z); o.w = f2bf(v.w);
    ((ushort4*)out)[i] = o;
}

// ---------------- W [K,M] fp32 -> WT [M,K] bf16 ----------------
__global__ __launch_bounds__(256) void transpose_cast_kernel(const float* __restrict__ W,
                                                             u16* __restrict__ WT) {
    __shared__ float tile[32][33];
    int m0 = blockIdx.x * 32, k0 = blockIdx.y * 32;
    int tx = threadIdx.x & 31, ty = threadIdx.x >> 5;  // 8 rows per pass
    #pragma unroll
    for (int i = 0; i < 4; i++) {
        int kk = ty + i * 8;
        tile[kk][tx] = W[(k0 + kk) * DD + m0 + tx];
    }
    __syncthreads();
    #pragma unroll
    for (int i = 0; i < 4; i++) {
        int mm = ty + i * 8;
        WT[(m0 + mm) * DD + k0 + tx] = f2bf(tile[tx][mm]);
    }
}

// ---------------- bf16 MFMA GEMM: C[N,1024] = A[N,1024] @ WT^T + bias ----------------
// MODE 0: write fp32  |  MODE 1: write bf16  |  MODE 2: write fp32 + res
template<int MODE>
__global__ __launch_bounds__(256)
void gemm_kernel(const u16* __restrict__ A, const u16* __restrict__ BT,
                 const float* __restrict__ bias, const float* __restrict__ res,
                 float* __restrict__ Cf, u16* __restrict__ Cb) {
    __shared__ u16 sA[128 * 32];
    __shared__ u16 sB[128 * 32];
    const int row0 = blockIdx.x * 128;
    const int col0 = blockIdx.y * 128;
    const int t = threadIdx.x;
    const int w = t >> 6, lane = t & 63;
    const int wr = (w >> 1) * 64, wc = (w & 1) * 64;
    const int m16 = lane & 15, quad = lane >> 4;

    f32x4 acc[4][4];
    #pragma unroll
    for (int i = 0; i < 4; i++)
        #pragma unroll
        for (int j = 0; j < 4; j++)
            acc[i][j] = (f32x4){0.f, 0.f, 0.f, 0.f};

    // staging: 2 16B chunks per thread per tile; elem offset = w*1024 + i*512 + lane*8
    const int e0 = w * 1024 + lane * 8;
    const int e1 = e0 + 512;
    const int r0 = e0 >> 5, c0 = e0 & 31;
    const int r1 = e1 >> 5, c1 = e1 & 31;
    const u16* Ag0 = A + (size_t)(row0 + r0) * DD + c0;
    const u16* Ag1 = A + (size_t)(row0 + r1) * DD + c1;
    const u16* Bg0 = BT + (size_t)(col0 + r0) * DD + c0;
    const u16* Bg1 = BT + (size_t)(col0 + r1) * DD + c1;

    for (int k0 = 0; k0 < DD; k0 += 32) {
        __syncthreads();
        load_lds16(Ag0 + k0, &sA[e0]);
        load_lds16(Ag1 + k0, &sA[e1]);
        load_lds16(Bg0 + k0, &sB[e0]);
        load_lds16(Bg1 + k0, &sB[e1]);
        __syncthreads();
        bf16x8 af[4], bfr[4];
        #pragma unroll
        for (int i = 0; i < 4; i++) {
            af[i]  = *(const bf16x8*)&sA[(wr + i * 16 + m16) * 32 + quad * 8];
            bfr[i] = *(const bf16x8*)&sB[(wc + i * 16 + m16) * 32 + quad * 8];
        }
        #pragma unroll
        for (int mi = 0; mi < 4; mi++)
            #pragma unroll
            for (int ni = 0; ni < 4; ni++)
                acc[mi][ni] = __builtin_amdgcn_mfma_f32_16x16x32_bf16(
                    af[mi], bfr[ni], acc[mi][ni], 0, 0, 0);
    }

    #pragma unroll
    for (int mi = 0; mi < 4; mi++) {
        #pragma unroll
        for (int r = 0; r < 4; r++) {
            int row = row0 + wr + mi * 16 + quad * 4 + r;
            #pragma unroll
            for (int ni = 0; ni < 4; ni++) {
                int col = col0 + wc + ni * 16 + m16;
                float v = acc[mi][ni][r] + bias[col];
                size_t idx = (size_t)row * DD + col;
                if (MODE == 0) Cf[idx] = v;
                else if (MODE == 1) Cb[idx] = f2bf(v);
                else Cf[idx] = v + res[idx];
            }
        }
    }
}

// ---------------- q_score[b,h,s] = (q[b,s,:]·Wqa[:,h] + bqa[h])*scale + mask ----------------
__global__ __launch_bounds__(256)
void qscore_kernel(const float* __restrict__ q, const float* __restrict__ Wqa,
                   const float* __restrict__ bqa, const float* __restrict__ mask,
                   float* __restrict__ qscore) {
    __shared__ float red[16][16][16];   // [row][seg][h]
    int t = threadIdx.x;
    int r = t >> 4, seg = t & 15;
    int grow = blockIdx.x * 16 + r;
    const float* qrow = q + (size_t)grow * DD + seg * 64;
    const float* wb = Wqa + (size_t)seg * 64 * HH;
    float acc[16];
    #pragma unroll
    for (int h = 0; h < 16; h++) acc[h] = 0.f;
    for (int i = 0; i < 16; i++) {                 // 16 float4 = 64 k per thread
        float4 qv = ((const float4*)qrow)[i];
        const float4* wr4 = (const float4*)(wb + i * 4 * HH);
        float qs[4] = {qv.x, qv.y, qv.z, qv.w};
        #pragma unroll
        for (int j = 0; j < 4; j++) {
            #pragma unroll
            for (int h4 = 0; h4 < 4; h4++) {
                float4 wv = wr4[j * 4 + h4];
                acc[h4 * 4 + 0] += qs[j] * wv.x;
                acc[h4 * 4 + 1] += qs[j] * wv.y;
                acc[h4 * 4 + 2] += qs[j] * wv.z;
                acc[h4 * 4 + 3] += qs[j] * wv.w;
            }
        }
    }
    #pragma unroll
    for (int h = 0; h < 16; h++) red[r][seg][h] = acc[h];
    __syncthreads();
    int rr = t >> 4, h = t & 15;
    float s = 0.f;
    #pragma unroll
    for (int i = 0; i < 16; i++) s += red[rr][i][h];
    int growr = blockIdx.x * 16 + rr;
    int b = growr >> 11, sidx = growr & 2047;
    float val = (s + bqa[h]) * 0.125f + mask[b * SS + sidx];
    qscore[((size_t)(b * HH + h) << 11) + sidx] = val;
}

// ---------------- softmax over S + pooled[b,h,d] = sum_s w[s]*X[b,s,h*64+d] ----------------
template<bool XBF16>
__global__ __launch_bounds__(256)
void softmax_pool_kernel(const float* __restrict__ score, const void* __restrict__ X,
                         float* __restrict__ pooled) {
    int bh = blockIdx.x;
    int b = bh >> 4, h = bh & 15;
    const float* srow = score + ((size_t)bh << 11);
    __shared__ float w[SS];
    __shared__ float rm[4], rs[4];
    __shared__ float pr[4][64];
    int t = threadIdx.x;

    float m = -1e30f;
    for (int s = t; s < SS; s += 256) { float v = srow[s]; w[s] = v; m = fmaxf(m, v); }
    #pragma unroll
    for (int off = 32; off; off >>= 1) m = fmaxf(m, __shfl_xor(m, off));
    if ((t & 63) == 0) rm[t >> 6] = m;
    __syncthreads();
    m = fmaxf(fmaxf(rm[0], rm[1]), fmaxf(rm[2], rm[3]));

    float sum = 0.f;
    for (int s = t; s < SS; s += 256) { float e = __expf(w[s] - m); w[s] = e; sum += e; }
    #pragma unroll
    for (int off = 32; off; off >>= 1) sum += __shfl_xor(sum, off);
    if ((t & 63) == 0) rs[t >> 6] = sum;
    __syncthreads();
    float inv = 1.0f / (rs[0] + rs[1] + rs[2] + rs[3]);

    int d = t & 63, sc = t >> 6;
    float acc = 0.f;
    if (!XBF16) {
        const float* xp = (const float*)X + (size_t)b * SS * DD + h * 64 + d;
        for (int s = sc; s < SS; s += 4) acc += w[s] * xp[(size_t)s * DD];
    } else {
        const u16* xp = (const u16*)X + (size_t)b * SS * DD + h * 64 + d;
        for (int s = sc; s < SS; s += 4) acc += w[s] * bf2f(xp[(size_t)s * DD]);
    }
    pr[sc][d] = acc;
    __syncthreads();
    if (t < 64) pooled[bh * 64 + t] = (pr[0][t] + pr[1][t] + pr[2][t] + pr[3][t]) * inv;
}

// ---------------- qk_score[b,h,s] = (k[b,s,h*64:]·pq[b,h,:])*scale + mask ----------------
__global__ __launch_bounds__(256)
void qkscore_kernel(const u16* __restrict__ kbf, const float* __restrict__ pq,
                    const float* __restrict__ mask, float* __restrict__ qkscore) {
    int row = blockIdx.x * 4 + (threadIdx.x >> 6);  // (b,s) row, one wave per row
    int lane = threadIdx.x & 63;
    int b = row >> 11, s = row & 2047;
    int h = lane >> 2, dp = lane & 3;
    const u16* kp = kbf + (size_t)row * DD + h * 64 + dp * 16;
    const float* pqp = pq + (size_t)(b * HH + h) * 64 + dp * 16;
    const uint4* kp4 = (const uint4*)kp;
    uint4 ka = kp4[0], kb4 = kp4[1];
    unsigned kw[8] = {ka.x, ka.y, ka.z, ka.w, kb4.x, kb4.y, kb4.z, kb4.w};
    float acc = 0.f;
    #pragma unroll
    for (int i = 0; i < 8; i++) {
        union { unsigned u; float f; } lo, hi;
        lo.u = kw[i] << 16;
        hi.u = kw[i] & 0xffff0000u;
        acc += lo.f * pqp[2 * i] + hi.f * pqp[2 * i + 1];
    }
    acc += __shfl_xor(acc, 1);
    acc += __shfl_xor(acc, 2);
    if (dp == 0) qkscore[(size_t)(b * HH + h) * SS + s] = acc * 0.125f + mask[b * SS + s];
}

// ---------------- weighted_bf[b,s,h*64+d] = bf16(pk[b,h,d]*q[b,s,h*64+d]) ----------------
__global__ __launch_bounds__(256)
void weighted_kernel(const float* __restrict__ q, const float* __restrict__ pk,
                     u16* __restrict__ wout) {
    int i = blockIdx.x * 256 + threadIdx.x;   // per float4
    int row = i >> 8;                          // 256 float4 per row
    int c0 = (i & 255) << 2;
    int b = row >> 11;
    int h = c0 >> 6, d = c0 & 63;
    float4 qv = ((const float4*)q)[i];
    const float4 pv = *(const float4*)(pk + (size_t)(b * HH + h) * 64 + d);
    ushort4 o;
    o.x = f2bf(qv.x * pv.x); o.y = f2bf(qv.y * pv.y);
    o.z = f2bf(qv.z * pv.z); o.w = f2bf(qv.w * pv.w);
    ((ushort4*)wout)[i] = o;
}

extern "C" void kernel_launch(void* const* d_in, const int* in_sizes, int n_in,
                              void* d_out, int out_size, void* d_ws, size_t ws_size,
                              hipStream_t stream) {
    const float* hs   = (const float*)d_in[0];
    const float* mask = (const float*)d_in[1];
    const float* Wq   = (const float*)d_in[2];
    const float* bq   = (const float*)d_in[3];
    const float* Wqa  = (const float*)d_in[4];
    const float* bqa  = (const float*)d_in[5];
    const float* Wk   = (const float*)d_in[6];
    const float* bk   = (const float*)d_in[7];
    const float* Wt   = (const float*)d_in[8];
    const float* bt   = (const float*)d_in[9];
    float* out = (float*)d_out;

    char* ws = (char*)d_ws;
    u16*   hs_bf = (u16*)ws;   ws += (size_t)NROWS * DD * 2;
    u16*   WqT   = (u16*)ws;   ws += (size_t)DD * DD * 2;
    u16*   WkT   = (u16*)ws;   ws += (size_t)DD * DD * 2;
    u16*   WtT   = (u16*)ws;   ws += (size_t)DD * DD * 2;
    float* q     = (float*)ws; ws += (size_t)NROWS * DD * 4;
    u16*   k_bf  = (u16*)ws;   ws += (size_t)NROWS * DD * 2;
    float* qsc   = (float*)ws; ws += (size_t)BB * HH * SS * 4;
    float* qksc  = (float*)ws; ws += (size_t)BB * HH * SS * 4;
    float* pq    = (float*)ws; ws += (size_t)BB * HH * 64 * 4;
    float* pk    = (float*)ws; ws += (size_t)BB * HH * 64 * 4;
    u16*   wbf   = (u16*)ws;   ws += (size_t)NROWS * DD * 2;

    int n4 = NROWS * DD / 4;
    cast_bf16_kernel<<<n4 / 256, 256, 0, stream>>>(hs, hs_bf, n4);
    transpose_cast_kernel<<<dim3(32, 32), 256, 0, stream>>>(Wq, WqT);
    transpose_cast_kernel<<<dim3(32, 32), 256, 0, stream>>>(Wk, WkT);
    transpose_cast_kernel<<<dim3(32, 32), 256, 0, stream>>>(Wt, WtT);

    gemm_kernel<0><<<dim3(NROWS / 128, DD / 128), 256, 0, stream>>>(hs_bf, WqT, bq, nullptr, q, nullptr);
    gemm_kernel<1><<<dim3(NROWS / 128, DD / 128), 256, 0, stream>>>(hs_bf, WkT, bk, nullptr, nullptr, k_bf);

    qscore_kernel<<<NROWS / 16, 256, 0, stream>>>(q, Wqa, bqa, mask, qsc);
    softmax_pool_kernel<false><<<BB * HH, 256, 0, stream>>>(qsc, q, pq);
    qkscore_kernel<<<NROWS / 4, 256, 0, stream>>>(k_bf, pq, mask, qksc);
    softmax_pool_kernel<true><<<BB * HH, 256, 0, stream>>>(qksc, k_bf, pk);
    weighted_kernel<<<n4 / 256, 256, 0, stream>>>(q, pk, wbf);

    gemm_kernel<2><<<dim3(NROWS / 128, DD / 128), 256, 0, stream>>>(wbf, WtT, bt, q, out, nullptr);
}

// Round 2
// 495.316 us; speedup vs baseline: 1.4565x; 1.4565x over previous
//
#include <hip/hip_runtime.h>
#include <hip/hip_bf16.h>
#include <math.h>

#define BB 8
#define SS 2048
#define DD 1024
#define HH 16
#define DHH 64
#define NROWS (BB*SS)   // 16384
#define SCHUNK 256

typedef unsigned short u16;
typedef __attribute__((ext_vector_type(8))) __bf16 bf16x8;
typedef __attribute__((ext_vector_type(4))) float f32x4;

__device__ __forceinline__ u16 f2bf(float f) {
    union { float f; unsigned u; } v; v.f = f;
    unsigned r = v.u + 0x7fffu + ((v.u >> 16) & 1u);
    return (u16)(r >> 16);
}
__device__ __forceinline__ float bf2f(u16 b) {
    union { unsigned u; float f; } v; v.u = ((unsigned)b) << 16;
    return v.f;
}

__device__ __forceinline__ void load_lds16(const void* g, void* l) {
    __builtin_amdgcn_global_load_lds(
        (const __attribute__((address_space(1))) unsigned int*)g,
        (__attribute__((address_space(3))) unsigned int*)l,
        16, 0, 0);
}

// ---------------- cast hs fp32 -> bf16 ----------------
__global__ __launch_bounds__(256) void cast_bf16_kernel(const float* __restrict__ in,
                                                        u16* __restrict__ out, int n4) {
    int i = blockIdx.x * 256 + threadIdx.x;
    if (i >= n4) return;
    float4 v = ((const float4*)in)[i];
    ushort4 o;
    o.x = f2bf(v.x); o.y = f2bf(v.y); o.z = f2bf(v.z); o.w = f2bf(v.w);
    ((ushort4*)out)[i] = o;
}

// ---------------- W [K,M] fp32 -> WT [M,K] bf16 ----------------
__global__ __launch_bounds__(256) void transpose_cast_kernel(const float* __restrict__ W,
                                                             u16* __restrict__ WT) {
    __shared__ float tile[32][33];
    int m0 = blockIdx.x * 32, k0 = blockIdx.y * 32;
    int tx = threadIdx.x & 31, ty = threadIdx.x >> 5;  // 8 rows per pass
    #pragma unroll
    for (int i = 0; i < 4; i++) {
        int kk = ty + i * 8;
        tile[kk][tx] = W[(k0 + kk) * DD + m0 + tx];
    }
    __syncthreads();
    #pragma unroll
    for (int i = 0; i < 4; i++) {
        int mm = ty + i * 8;
        WT[(m0 + mm) * DD + k0 + tx] = f2bf(tile[tx][mm]);
    }
}

// ---------------- bf16 MFMA GEMM: C[N,1024] = A[N,1024] @ WT^T + bias ----------------
// MODE 0: write fp32  |  MODE 1: write bf16  |  MODE 2: write fp32 + res
template<int MODE>
__global__ __launch_bounds__(256)
void gemm_kernel(const u16* __restrict__ A, const u16* __restrict__ BT,
                 const float* __restrict__ bias, const float* __restrict__ res,
                 float* __restrict__ Cf, u16* __restrict__ Cb) {
    __shared__ u16 sA[128 * 32];
    __shared__ u16 sB[128 * 32];
    const int row0 = blockIdx.x * 128;
    const int col0 = blockIdx.y * 128;
    const int t = threadIdx.x;
    const int w = t >> 6, lane = t & 63;
    const int wr = (w >> 1) * 64, wc = (w & 1) * 64;
    const int m16 = lane & 15, quad = lane >> 4;

    f32x4 acc[4][4];
    #pragma unroll
    for (int i = 0; i < 4; i++)
        #pragma unroll
        for (int j = 0; j < 4; j++)
            acc[i][j] = (f32x4){0.f, 0.f, 0.f, 0.f};

    // staging: 2 16B chunks per thread per tile; elem offset = w*1024 + i*512 + lane*8
    const int e0 = w * 1024 + lane * 8;
    const int e1 = e0 + 512;
    const int r0 = e0 >> 5, c0 = e0 & 31;
    const int r1 = e1 >> 5, c1 = e1 & 31;
    const u16* Ag0 = A + (size_t)(row0 + r0) * DD + c0;
    const u16* Ag1 = A + (size_t)(row0 + r1) * DD + c1;
    const u16* Bg0 = BT + (size_t)(col0 + r0) * DD + c0;
    const u16* Bg1 = BT + (size_t)(col0 + r1) * DD + c1;

    for (int k0 = 0; k0 < DD; k0 += 32) {
        __syncthreads();
        load_lds16(Ag0 + k0, &sA[e0]);
        load_lds16(Ag1 + k0, &sA[e1]);
        load_lds16(Bg0 + k0, &sB[e0]);
        load_lds16(Bg1 + k0, &sB[e1]);
        __syncthreads();
        bf16x8 af[4], bfr[4];
        #pragma unroll
        for (int i = 0; i < 4; i++) {
            af[i]  = *(const bf16x8*)&sA[(wr + i * 16 + m16) * 32 + quad * 8];
            bfr[i] = *(const bf16x8*)&sB[(wc + i * 16 + m16) * 32 + quad * 8];
        }
        #pragma unroll
        for (int mi = 0; mi < 4; mi++)
            #pragma unroll
            for (int ni = 0; ni < 4; ni++)
                acc[mi][ni] = __builtin_amdgcn_mfma_f32_16x16x32_bf16(
                    af[mi], bfr[ni], acc[mi][ni], 0, 0, 0);
    }

    #pragma unroll
    for (int mi = 0; mi < 4; mi++) {
        #pragma unroll
        for (int r = 0; r < 4; r++) {
            int row = row0 + wr + mi * 16 + quad * 4 + r;
            #pragma unroll
            for (int ni = 0; ni < 4; ni++) {
                int col = col0 + wc + ni * 16 + m16;
                float v = acc[mi][ni][r] + bias[col];
                size_t idx = (size_t)row * DD + col;
                if (MODE == 0) Cf[idx] = v;
                else if (MODE == 1) Cb[idx] = f2bf(v);
                else Cf[idx] = v + res[idx];
            }
        }
    }
}

// ---------------- q_score[b,h,s] = (q[b,s,:]·Wqa[:,h] + bqa[h])*scale + mask ----------------
__global__ __launch_bounds__(256)
void qscore_kernel(const float* __restrict__ q, const float* __restrict__ Wqa,
                   const float* __restrict__ bqa, const float* __restrict__ mask,
                   float* __restrict__ qscore) {
    __shared__ float red[16][16][16];   // [row][seg][h]
    int t = threadIdx.x;
    int r = t >> 4, seg = t & 15;
    int grow = blockIdx.x * 16 + r;
    const float* qrow = q + (size_t)grow * DD + seg * 64;
    const float* wb = Wqa + (size_t)seg * 64 * HH;
    float acc[16];
    #pragma unroll
    for (int h = 0; h < 16; h++) acc[h] = 0.f;
    for (int i = 0; i < 16; i++) {                 // 16 float4 = 64 k per thread
        float4 qv = ((const float4*)qrow)[i];
        const float4* wr4 = (const float4*)(wb + i * 4 * HH);
        float qs[4] = {qv.x, qv.y, qv.z, qv.w};
        #pragma unroll
        for (int j = 0; j < 4; j++) {
            #pragma unroll
            for (int h4 = 0; h4 < 4; h4++) {
                float4 wv = wr4[j * 4 + h4];
                acc[h4 * 4 + 0] += qs[j] * wv.x;
                acc[h4 * 4 + 1] += qs[j] * wv.y;
                acc[h4 * 4 + 2] += qs[j] * wv.z;
                acc[h4 * 4 + 3] += qs[j] * wv.w;
            }
        }
    }
    #pragma unroll
    for (int h = 0; h < 16; h++) red[r][seg][h] = acc[h];
    __syncthreads();
    int rr = t >> 4, h = t & 15;
    float s = 0.f;
    #pragma unroll
    for (int i = 0; i < 16; i++) s += red[rr][i][h];
    int growr = blockIdx.x * 16 + rr;
    int b = growr >> 11, sidx = growr & 2047;
    float val = (s + bqa[h]) * 0.125f + mask[b * SS + sidx];
    qscore[((size_t)(b * HH + h) << 11) + sidx] = val;
}

// ---------------- softmax over S, in place: score[bh,:] -> normalized weights ----------------
__global__ __launch_bounds__(256)
void softmax_kernel(float* __restrict__ score) {
    int bh = blockIdx.x;
    float* srow = score + ((size_t)bh << 11);
    __shared__ float rm[4], rs[4];
    int t = threadIdx.x;

    float v[8];
    float m = -1e30f;
    #pragma unroll
    for (int i = 0; i < 8; i++) { v[i] = srow[t + i * 256]; m = fmaxf(m, v[i]); }
    #pragma unroll
    for (int off = 32; off; off >>= 1) m = fmaxf(m, __shfl_xor(m, off));
    if ((t & 63) == 0) rm[t >> 6] = m;
    __syncthreads();
    m = fmaxf(fmaxf(rm[0], rm[1]), fmaxf(rm[2], rm[3]));

    float sum = 0.f;
    #pragma unroll
    for (int i = 0; i < 8; i++) { v[i] = __expf(v[i] - m); sum += v[i]; }
    #pragma unroll
    for (int off = 32; off; off >>= 1) sum += __shfl_xor(sum, off);
    if ((t & 63) == 0) rs[t >> 6] = sum;
    __syncthreads();
    float inv = 1.0f / (rs[0] + rs[1] + rs[2] + rs[3]);
    #pragma unroll
    for (int i = 0; i < 8; i++) srow[t + i * 256] = v[i] * inv;
}

// ---------------- pooled[b,h,d] += sum_{s in chunk} w[bh,s] * X[b,s,h*64+d] ----------------
// grid = (BB*HH, SS/SCHUNK); pooled must be zeroed before launch.
template<bool XBF16>
__global__ __launch_bounds__(256)
void pool_kernel(const float* __restrict__ w, const void* __restrict__ X,
                 float* __restrict__ pooled) {
    int bh = blockIdx.x;
    int b = bh >> 4, h = bh & 15;
    int s0 = blockIdx.y * SCHUNK;
    int lane = threadIdx.x & 63, wid = threadIdx.x >> 6;
    const float* wrow = w + ((size_t)bh << 11);
    float acc = 0.f;
    if (!XBF16) {
        const float* xp = (const float*)X + (size_t)b * SS * DD + h * 64 + lane;
        for (int i = wid; i < SCHUNK; i += 4) {
            int s = s0 + i;
            acc += wrow[s] * xp[(size_t)s * DD];
        }
    } else {
        const u16* xp = (const u16*)X + (size_t)b * SS * DD + h * 64 + lane;
        for (int i = wid; i < SCHUNK; i += 4) {
            int s = s0 + i;
            acc += wrow[s] * bf2f(xp[(size_t)s * DD]);
        }
    }
    __shared__ float pr[4][64];
    pr[wid][lane] = acc;
    __syncthreads();
    if (threadIdx.x < 64) {
        float v = pr[0][threadIdx.x] + pr[1][threadIdx.x] +
                  pr[2][threadIdx.x] + pr[3][threadIdx.x];
        atomicAdd(&pooled[bh * 64 + threadIdx.x], v);
    }
}

// ---------------- qk_score[b,h,s] = (k[b,s,h*64:]·pq[b,h,:])*scale + mask ----------------
__global__ __launch_bounds__(256)
void qkscore_kernel(const u16* __restrict__ kbf, const float* __restrict__ pq,
                    const float* __restrict__ mask, float* __restrict__ qkscore) {
    int row = blockIdx.x * 4 + (threadIdx.x >> 6);  // (b,s) row, one wave per row
    int lane = threadIdx.x & 63;
    int b = row >> 11, s = row & 2047;
    int h = lane >> 2, dp = lane & 3;
    const u16* kp = kbf + (size_t)row * DD + h * 64 + dp * 16;
    const float* pqp = pq + (size_t)(b * HH + h) * 64 + dp * 16;
    const uint4* kp4 = (const uint4*)kp;
    uint4 ka = kp4[0], kb4 = kp4[1];
    unsigned kw[8] = {ka.x, ka.y, ka.z, ka.w, kb4.x, kb4.y, kb4.z, kb4.w};
    float acc = 0.f;
    #pragma unroll
    for (int i = 0; i < 8; i++) {
        union { unsigned u; float f; } lo, hi;
        lo.u = kw[i] << 16;
        hi.u = kw[i] & 0xffff0000u;
        acc += lo.f * pqp[2 * i] + hi.f * pqp[2 * i + 1];
    }
    acc += __shfl_xor(acc, 1);
    acc += __shfl_xor(acc, 2);
    if (dp == 0) qkscore[(size_t)(b * HH + h) * SS + s] = acc * 0.125f + mask[b * SS + s];
}

// ---------------- weighted_bf[b,s,h*64+d] = bf16(pk[b,h,d]*q[b,s,h*64+d]) ----------------
__global__ __launch_bounds__(256)
void weighted_kernel(const float* __restrict__ q, const float* __restrict__ pk,
                     u16* __restrict__ wout) {
    int i = blockIdx.x * 256 + threadIdx.x;   // per float4
    int row = i >> 8;                          // 256 float4 per row
    int c0 = (i & 255) << 2;
    int b = row >> 11;
    int h = c0 >> 6, d = c0 & 63;
    float4 qv = ((const float4*)q)[i];
    const float4 pv = *(const float4*)(pk + (size_t)(b * HH + h) * 64 + d);
    ushort4 o;
    o.x = f2bf(qv.x * pv.x); o.y = f2bf(qv.y * pv.y);
    o.z = f2bf(qv.z * pv.z); o.w = f2bf(qv.w * pv.w);
    ((ushort4*)wout)[i] = o;
}

extern "C" void kernel_launch(void* const* d_in, const int* in_sizes, int n_in,
                              void* d_out, int out_size, void* d_ws, size_t ws_size,
                              hipStream_t stream) {
    const float* hs   = (const float*)d_in[0];
    const float* mask = (const float*)d_in[1];
    const float* Wq   = (const float*)d_in[2];
    const float* bq   = (const float*)d_in[3];
    const float* Wqa  = (const float*)d_in[4];
    const float* bqa  = (const float*)d_in[5];
    const float* Wk   = (const float*)d_in[6];
    const float* bk   = (const float*)d_in[7];
    const float* Wt   = (const float*)d_in[8];
    const float* bt   = (const float*)d_in[9];
    float* out = (float*)d_out;

    char* ws = (char*)d_ws;
    u16*   hs_bf = (u16*)ws;   ws += (size_t)NROWS * DD * 2;
    u16*   WqT   = (u16*)ws;   ws += (size_t)DD * DD * 2;
    u16*   WkT   = (u16*)ws;   ws += (size_t)DD * DD * 2;
    u16*   WtT   = (u16*)ws;   ws += (size_t)DD * DD * 2;
    float* q     = (float*)ws; ws += (size_t)NROWS * DD * 4;
    u16*   k_bf  = (u16*)ws;   ws += (size_t)NROWS * DD * 2;
    float* qsc   = (float*)ws; ws += (size_t)BB * HH * SS * 4;
    float* qksc  = (float*)ws; ws += (size_t)BB * HH * SS * 4;
    float* pq    = (float*)ws; ws += (size_t)BB * HH * 64 * 4;
    float* pk    = (float*)ws; ws += (size_t)BB * HH * 64 * 4;
    u16*   wbf   = (u16*)ws;   ws += (size_t)NROWS * DD * 2;

    int n4 = NROWS * DD / 4;
    cast_bf16_kernel<<<n4 / 256, 256, 0, stream>>>(hs, hs_bf, n4);
    transpose_cast_kernel<<<dim3(32, 32), 256, 0, stream>>>(Wq, WqT);
    transpose_cast_kernel<<<dim3(32, 32), 256, 0, stream>>>(Wk, WkT);
    transpose_cast_kernel<<<dim3(32, 32), 256, 0, stream>>>(Wt, WtT);

    // zero the atomic-accumulated pooled buffers (ws is poisoned 0xAA each call)
    hipMemsetAsync(pq, 0, (size_t)BB * HH * 64 * 4, stream);
    hipMemsetAsync(pk, 0, (size_t)BB * HH * 64 * 4, stream);

    gemm_kernel<0><<<dim3(NROWS / 128, DD / 128), 256, 0, stream>>>(hs_bf, WqT, bq, nullptr, q, nullptr);
    gemm_kernel<1><<<dim3(NROWS / 128, DD / 128), 256, 0, stream>>>(hs_bf, WkT, bk, nullptr, nullptr, k_bf);

    qscore_kernel<<<NROWS / 16, 256, 0, stream>>>(q, Wqa, bqa, mask, qsc);
    softmax_kernel<<<BB * HH, 256, 0, stream>>>(qsc);
    pool_kernel<false><<<dim3(BB * HH, SS / SCHUNK), 256, 0, stream>>>(qsc, q, pq);
    qkscore_kernel<<<NROWS / 4, 256, 0, stream>>>(k_bf, pq, mask, qksc);
    softmax_kernel<<<BB * HH, 256, 0, stream>>>(qksc);
    pool_kernel<true><<<dim3(BB * HH, SS / SCHUNK), 256, 0, stream>>>(qksc, k_bf, pk);
    weighted_kernel<<<n4 / 256, 256, 0, stream>>>(q, pk, wbf);

    gemm_kernel<2><<<dim3(NROWS / 128, DD / 128), 256, 0, stream>>>(wbf, WtT, bt, q, out, nullptr);
}

// Round 3
// 399.310 us; speedup vs baseline: 1.8066x; 1.2404x over previous
//
#include <hip/hip_runtime.h>
#include <hip/hip_bf16.h>
#include <math.h>

#define BB 8
#define SS 2048
#define DD 1024
#define HH 16
#define DHH 64
#define NROWS (BB*SS)   // 16384
#define SCHUNK 256

typedef unsigned short u16;
typedef __attribute__((ext_vector_type(8))) __bf16 bf16x8;
typedef __attribute__((ext_vector_type(4))) float f32x4;

__device__ __forceinline__ u16 f2bf(float f) {
    union { float f; unsigned u; } v; v.f = f;
    unsigned r = v.u + 0x7fffu + ((v.u >> 16) & 1u);
    return (u16)(r >> 16);
}
__device__ __forceinline__ float bf2f(u16 b) {
    union { unsigned u; float f; } v; v.u = ((unsigned)b) << 16;
    return v.f;
}

__device__ __forceinline__ void load_lds16(const void* g, void* l) {
    __builtin_amdgcn_global_load_lds(
        (const __attribute__((address_space(1))) unsigned int*)g,
        (__attribute__((address_space(3))) unsigned int*)l,
        16, 0, 0);
}

// ---------------- cast hs fp32 -> bf16 ----------------
__global__ __launch_bounds__(256) void cast_bf16_kernel(const float* __restrict__ in,
                                                        u16* __restrict__ out, int n4) {
    int i = blockIdx.x * 256 + threadIdx.x;
    if (i >= n4) return;
    float4 v = ((const float4*)in)[i];
    ushort4 o;
    o.x = f2bf(v.x); o.y = f2bf(v.y); o.z = f2bf(v.z); o.w = f2bf(v.w);
    ((ushort4*)out)[i] = o;
}

// ---------------- W [K,M] fp32 -> WT [M,K] bf16 ----------------
__global__ __launch_bounds__(256) void transpose_cast_kernel(const float* __restrict__ W,
                                                             u16* __restrict__ WT) {
    __shared__ float tile[32][33];
    int m0 = blockIdx.x * 32, k0 = blockIdx.y * 32;
    int tx = threadIdx.x & 31, ty = threadIdx.x >> 5;
    #pragma unroll
    for (int i = 0; i < 4; i++) {
        int kk = ty + i * 8;
        tile[kk][tx] = W[(k0 + kk) * DD + m0 + tx];
    }
    __syncthreads();
    #pragma unroll
    for (int i = 0; i < 4; i++) {
        int mm = ty + i * 8;
        WT[(m0 + mm) * DD + k0 + tx] = f2bf(tile[tx][mm]);
    }
}

// ---------------- Wqa [1024][16] fp32 -> WqaT [16][1024] bf16 ----------------
__global__ __launch_bounds__(256) void wqa_transpose_kernel(const float* __restrict__ Wqa,
                                                            u16* __restrict__ WqaT) {
    int i = blockIdx.x * 256 + threadIdx.x;   // 16384 total
    int h = i >> 10, k = i & 1023;
    WqaT[i] = f2bf(Wqa[k * HH + h]);
}

// ---------------- bf16 MFMA GEMM: C[N,1024] = A[N,1024] @ WT^T + bias ----------------
// MODE 0: fp32 | MODE 1: bf16 | MODE 2: fp32 + res | MODE 3: fp32 AND bf16
template<int MODE>
__global__ __launch_bounds__(256)
void gemm_kernel(const u16* __restrict__ A, const u16* __restrict__ BT,
                 const float* __restrict__ bias, const float* __restrict__ res,
                 float* __restrict__ Cf, u16* __restrict__ Cb) {
    __shared__ u16 sA[128 * 32];
    __shared__ u16 sB[128 * 32];
    const int row0 = blockIdx.x * 128;
    const int col0 = blockIdx.y * 128;
    const int t = threadIdx.x;
    const int w = t >> 6, lane = t & 63;
    const int wr = (w >> 1) * 64, wc = (w & 1) * 64;
    const int m16 = lane & 15, quad = lane >> 4;

    f32x4 acc[4][4];
    #pragma unroll
    for (int i = 0; i < 4; i++)
        #pragma unroll
        for (int j = 0; j < 4; j++)
            acc[i][j] = (f32x4){0.f, 0.f, 0.f, 0.f};

    const int e0 = w * 1024 + lane * 8;
    const int e1 = e0 + 512;
    const int r0 = e0 >> 5, c0 = e0 & 31;
    const int r1 = e1 >> 5, c1 = e1 & 31;
    const u16* Ag0 = A + (size_t)(row0 + r0) * DD + c0;
    const u16* Ag1 = A + (size_t)(row0 + r1) * DD + c1;
    const u16* Bg0 = BT + (size_t)(col0 + r0) * DD + c0;
    const u16* Bg1 = BT + (size_t)(col0 + r1) * DD + c1;

    for (int k0 = 0; k0 < DD; k0 += 32) {
        __syncthreads();
        load_lds16(Ag0 + k0, &sA[e0]);
        load_lds16(Ag1 + k0, &sA[e1]);
        load_lds16(Bg0 + k0, &sB[e0]);
        load_lds16(Bg1 + k0, &sB[e1]);
        __syncthreads();
        bf16x8 af[4], bfr[4];
        #pragma unroll
        for (int i = 0; i < 4; i++) {
            af[i]  = *(const bf16x8*)&sA[(wr + i * 16 + m16) * 32 + quad * 8];
            bfr[i] = *(const bf16x8*)&sB[(wc + i * 16 + m16) * 32 + quad * 8];
        }
        #pragma unroll
        for (int mi = 0; mi < 4; mi++)
            #pragma unroll
            for (int ni = 0; ni < 4; ni++)
                acc[mi][ni] = __builtin_amdgcn_mfma_f32_16x16x32_bf16(
                    af[mi], bfr[ni], acc[mi][ni], 0, 0, 0);
    }

    #pragma unroll
    for (int mi = 0; mi < 4; mi++) {
        #pragma unroll
        for (int r = 0; r < 4; r++) {
            int row = row0 + wr + mi * 16 + quad * 4 + r;
            #pragma unroll
            for (int ni = 0; ni < 4; ni++) {
                int col = col0 + wc + ni * 16 + m16;
                float v = acc[mi][ni][r] + bias[col];
                size_t idx = (size_t)row * DD + col;
                if (MODE == 0) Cf[idx] = v;
                else if (MODE == 1) Cb[idx] = f2bf(v);
                else if (MODE == 2) Cf[idx] = v + res[idx];
                else { Cf[idx] = v; Cb[idx] = f2bf(v); }
            }
        }
    }
}

// ---------------- raw qscore via MFMA, K-split 4, atomic accumulate ----------------
// grid = (NROWS/64, 4); qraw must be zeroed. qraw[bh][s] += sum_k q[s][k]*Wqa[k][h]
__global__ __launch_bounds__(256)
void qscore_mfma_kernel(const u16* __restrict__ qbf, const u16* __restrict__ WqaT,
                        float* __restrict__ qraw) {
    int w = threadIdx.x >> 6, lane = threadIdx.x & 63;
    int row0 = blockIdx.x * 64 + w * 16;
    int kbase = blockIdx.y * 256;
    int m16 = lane & 15, quad = lane >> 4;
    f32x4 acc = (f32x4){0.f, 0.f, 0.f, 0.f};
    const u16* ap = qbf + (size_t)(row0 + m16) * DD + kbase + quad * 8;
    const u16* bp = WqaT + (size_t)m16 * DD + kbase + quad * 8;
    #pragma unroll
    for (int kk = 0; kk < 256; kk += 32) {
        bf16x8 a = *(const bf16x8*)(ap + kk);
        bf16x8 b = *(const bf16x8*)(bp + kk);
        acc = __builtin_amdgcn_mfma_f32_16x16x32_bf16(a, b, acc, 0, 0, 0);
    }
    #pragma unroll
    for (int r = 0; r < 4; r++) {
        int grow = row0 + quad * 4 + r;
        int b = grow >> 11, sidx = grow & 2047;
        atomicAdd(&qraw[((size_t)(b * HH + m16) << 11) + sidx], acc[r]);
    }
}

// ---------------- softmax over S, in place; EPI: apply (v+bqa[h])*scale+mask first ----------------
template<bool EPI>
__global__ __launch_bounds__(256)
void softmax_kernel(float* __restrict__ score, const float* __restrict__ bqa,
                    const float* __restrict__ mask) {
    int bh = blockIdx.x;
    int b = bh >> 4, h = bh & 15;
    float* srow = score + ((size_t)bh << 11);
    __shared__ float rm[4], rs[4];
    int t = threadIdx.x;

    float v[8];
    float m = -1e30f;
    #pragma unroll
    for (int i = 0; i < 8; i++) {
        float x = srow[t + i * 256];
        if (EPI) x = (x + bqa[h]) * 0.125f + mask[b * SS + t + i * 256];
        v[i] = x; m = fmaxf(m, x);
    }
    #pragma unroll
    for (int off = 32; off; off >>= 1) m = fmaxf(m, __shfl_xor(m, off));
    if ((t & 63) == 0) rm[t >> 6] = m;
    __syncthreads();
    m = fmaxf(fmaxf(rm[0], rm[1]), fmaxf(rm[2], rm[3]));

    float sum = 0.f;
    #pragma unroll
    for (int i = 0; i < 8; i++) { v[i] = __expf(v[i] - m); sum += v[i]; }
    #pragma unroll
    for (int off = 32; off; off >>= 1) sum += __shfl_xor(sum, off);
    if ((t & 63) == 0) rs[t >> 6] = sum;
    __syncthreads();
    float inv = 1.0f / (rs[0] + rs[1] + rs[2] + rs[3]);
    #pragma unroll
    for (int i = 0; i < 8; i++) srow[t + i * 256] = v[i] * inv;
}

// ---------------- pooled[b,h,d] += sum_{s in chunk} w[bh,s] * X_bf16[b,s,h*64+d] ----------------
__global__ __launch_bounds__(256)
void pool_kernel(const float* __restrict__ w, const u16* __restrict__ X,
                 float* __restrict__ pooled) {
    int bh = blockIdx.x;
    int b = bh >> 4, h = bh & 15;
    int s0 = blockIdx.y * SCHUNK;
    int lane = threadIdx.x & 63, wid = threadIdx.x >> 6;
    const float* wrow = w + ((size_t)bh << 11);
    float acc = 0.f;
    const u16* xp = X + (size_t)b * SS * DD + h * 64 + lane;
    for (int i = wid; i < SCHUNK; i += 4) {
        int s = s0 + i;
        acc += wrow[s] * bf2f(xp[(size_t)s * DD]);
    }
    __shared__ float pr[4][64];
    pr[wid][lane] = acc;
    __syncthreads();
    if (threadIdx.x < 64) {
        float v = pr[0][threadIdx.x] + pr[1][threadIdx.x] +
                  pr[2][threadIdx.x] + pr[3][threadIdx.x];
        atomicAdd(&pooled[bh * 64 + threadIdx.x], v);
    }
}

// ---------------- qk_score[b,h,s] = (k[b,s,h*64:]·pq[b,h,:])*scale + mask ----------------
__global__ __launch_bounds__(256)
void qkscore_kernel(const u16* __restrict__ kbf, const float* __restrict__ pq,
                    const float* __restrict__ mask, float* __restrict__ qkscore) {
    int row = blockIdx.x * 4 + (threadIdx.x >> 6);
    int lane = threadIdx.x & 63;
    int b = row >> 11, s = row & 2047;
    int h = lane >> 2, dp = lane & 3;
    const u16* kp = kbf + (size_t)row * DD + h * 64 + dp * 16;
    const float* pqp = pq + (size_t)(b * HH + h) * 64 + dp * 16;
    const uint4* kp4 = (const uint4*)kp;
    uint4 ka = kp4[0], kb4 = kp4[1];
    unsigned kw[8] = {ka.x, ka.y, ka.z, ka.w, kb4.x, kb4.y, kb4.z, kb4.w};
    float acc = 0.f;
    #pragma unroll
    for (int i = 0; i < 8; i++) {
        union { unsigned u; float f; } lo, hi;
        lo.u = kw[i] << 16;
        hi.u = kw[i] & 0xffff0000u;
        acc += lo.f * pqp[2 * i] + hi.f * pqp[2 * i + 1];
    }
    acc += __shfl_xor(acc, 1);
    acc += __shfl_xor(acc, 2);
    if (dp == 0) qkscore[(size_t)(b * HH + h) * SS + s] = acc * 0.125f + mask[b * SS + s];
}

// ---------------- weighted_bf[b,s,h*64+d] = bf16(pk[b,h,d]*q_bf[b,s,h*64+d]) ----------------
__global__ __launch_bounds__(256)
void weighted_kernel(const u16* __restrict__ qbf, const float* __restrict__ pk,
                     u16* __restrict__ wout) {
    int i = blockIdx.x * 256 + threadIdx.x;   // per ushort4 (4 elems)
    int row = i >> 8;
    int c0 = (i & 255) << 2;
    int b = row >> 11;
    int h = c0 >> 6, d = c0 & 63;
    ushort4 qv = ((const ushort4*)qbf)[i];
    const float4 pv = *(const float4*)(pk + (size_t)(b * HH + h) * 64 + d);
    ushort4 o;
    o.x = f2bf(bf2f(qv.x) * pv.x); o.y = f2bf(bf2f(qv.y) * pv.y);
    o.z = f2bf(bf2f(qv.z) * pv.z); o.w = f2bf(bf2f(qv.w) * pv.w);
    ((ushort4*)wout)[i] = o;
}

extern "C" void kernel_launch(void* const* d_in, const int* in_sizes, int n_in,
                              void* d_out, int out_size, void* d_ws, size_t ws_size,
                              hipStream_t stream) {
    const float* hs   = (const float*)d_in[0];
    const float* mask = (const float*)d_in[1];
    const float* Wq   = (const float*)d_in[2];
    const float* bq   = (const float*)d_in[3];
    const float* Wqa  = (const float*)d_in[4];
    const float* bqa  = (const float*)d_in[5];
    const float* Wk   = (const float*)d_in[6];
    const float* bk   = (const float*)d_in[7];
    const float* Wt   = (const float*)d_in[8];
    const float* bt   = (const float*)d_in[9];
    float* out = (float*)d_out;

    char* ws = (char*)d_ws;
    u16*   hs_bf = (u16*)ws;   ws += (size_t)NROWS * DD * 2;
    u16*   WqT   = (u16*)ws;   ws += (size_t)DD * DD * 2;
    u16*   WkT   = (u16*)ws;   ws += (size_t)DD * DD * 2;
    u16*   WtT   = (u16*)ws;   ws += (size_t)DD * DD * 2;
    u16*   WqaT  = (u16*)ws;   ws += (size_t)HH * DD * 2;
    float* q     = (float*)ws; ws += (size_t)NROWS * DD * 4;
    u16*   q_bf  = (u16*)ws;   ws += (size_t)NROWS * DD * 2;
    u16*   k_bf  = (u16*)ws;   ws += (size_t)NROWS * DD * 2;
    float* qsc   = (float*)ws; ws += (size_t)BB * HH * SS * 4;
    float* qksc  = (float*)ws; ws += (size_t)BB * HH * SS * 4;
    float* pq    = (float*)ws; ws += (size_t)BB * HH * 64 * 4;
    float* pk    = (float*)ws; ws += (size_t)BB * HH * 64 * 4;
    u16*   wbf   = hs_bf;  // alias: hs_bf dead after gemm<1>, wbf written after

    int n4 = NROWS * DD / 4;
    cast_bf16_kernel<<<n4 / 256, 256, 0, stream>>>(hs, hs_bf, n4);
    transpose_cast_kernel<<<dim3(32, 32), 256, 0, stream>>>(Wq, WqT);
    transpose_cast_kernel<<<dim3(32, 32), 256, 0, stream>>>(Wk, WkT);
    transpose_cast_kernel<<<dim3(32, 32), 256, 0, stream>>>(Wt, WtT);
    wqa_transpose_kernel<<<HH * DD / 256, 256, 0, stream>>>(Wqa, WqaT);

    hipMemsetAsync(qsc, 0, (size_t)BB * HH * SS * 4, stream);
    hipMemsetAsync(pq, 0, (size_t)BB * HH * 64 * 4, stream);
    hipMemsetAsync(pk, 0, (size_t)BB * HH * 64 * 4, stream);

    gemm_kernel<3><<<dim3(NROWS / 128, DD / 128), 256, 0, stream>>>(hs_bf, WqT, bq, nullptr, q, q_bf);
    gemm_kernel<1><<<dim3(NROWS / 128, DD / 128), 256, 0, stream>>>(hs_bf, WkT, bk, nullptr, nullptr, k_bf);

    qscore_mfma_kernel<<<dim3(NROWS / 64, 4), 256, 0, stream>>>(q_bf, WqaT, qsc);
    softmax_kernel<true><<<BB * HH, 256, 0, stream>>>(qsc, bqa, mask);
    pool_kernel<<<dim3(BB * HH, SS / SCHUNK), 256, 0, stream>>>(qsc, q_bf, pq);
    qkscore_kernel<<<NROWS / 4, 256, 0, stream>>>(k_bf, pq, mask, qksc);
    softmax_kernel<false><<<BB * HH, 256, 0, stream>>>(qksc, nullptr, nullptr);
    pool_kernel<<<dim3(BB * HH, SS / SCHUNK), 256, 0, stream>>>(qksc, k_bf, pk);
    weighted_kernel<<<n4 / 256, 256, 0, stream>>>(q_bf, pk, wbf);

    gemm_kernel<2><<<dim3(NROWS / 128, DD / 128), 256, 0, stream>>>(wbf, WtT, bt, q, out, nullptr);
}

// Round 4
// 330.710 us; speedup vs baseline: 2.1814x; 1.2074x over previous
//
#include <hip/hip_runtime.h>
#include <hip/hip_bf16.h>
#include <math.h>

#define BB 8
#define SS 2048
#define DD 1024
#define HH 16
#define DHH 64
#define NROWS (BB*SS)   // 16384
#define QSLICE ((size_t)BB * HH * SS)   // elems per qscore K-split slice

typedef unsigned short u16;
typedef __attribute__((ext_vector_type(8))) __bf16 bf16x8;
typedef __attribute__((ext_vector_type(4))) float f32x4;

__device__ __forceinline__ u16 f2bf(float f) {
    union { float f; unsigned u; } v; v.f = f;
    unsigned r = v.u + 0x7fffu + ((v.u >> 16) & 1u);
    return (u16)(r >> 16);
}
__device__ __forceinline__ float bf2f(u16 b) {
    union { unsigned u; float f; } v; v.u = ((unsigned)b) << 16;
    return v.f;
}

__device__ __forceinline__ void load_lds16(const void* g, void* l) {
    __builtin_amdgcn_global_load_lds(
        (const __attribute__((address_space(1))) unsigned int*)g,
        (__attribute__((address_space(3))) unsigned int*)l,
        16, 0, 0);
}

// ---------------- cast hs fp32 -> bf16 ----------------
__global__ __launch_bounds__(256) void cast_bf16_kernel(const float* __restrict__ in,
                                                        u16* __restrict__ out, int n4) {
    int i = blockIdx.x * 256 + threadIdx.x;
    if (i >= n4) return;
    float4 v = ((const float4*)in)[i];
    ushort4 o;
    o.x = f2bf(v.x); o.y = f2bf(v.y); o.z = f2bf(v.z); o.w = f2bf(v.w);
    ((ushort4*)out)[i] = o;
}

// ---------------- W [K,M] fp32 -> WT [M,K] bf16 ----------------
__global__ __launch_bounds__(256) void transpose_cast_kernel(const float* __restrict__ W,
                                                             u16* __restrict__ WT) {
    __shared__ float tile[32][33];
    int m0 = blockIdx.x * 32, k0 = blockIdx.y * 32;
    int tx = threadIdx.x & 31, ty = threadIdx.x >> 5;
    #pragma unroll
    for (int i = 0; i < 4; i++) {
        int kk = ty + i * 8;
        tile[kk][tx] = W[(k0 + kk) * DD + m0 + tx];
    }
    __syncthreads();
    #pragma unroll
    for (int i = 0; i < 4; i++) {
        int mm = ty + i * 8;
        WT[(m0 + mm) * DD + k0 + tx] = f2bf(tile[tx][mm]);
    }
}

// ---------------- Wqa [1024][16] fp32 -> WqaT [16][1024] bf16 ----------------
__global__ __launch_bounds__(256) void wqa_transpose_kernel(const float* __restrict__ Wqa,
                                                            u16* __restrict__ WqaT) {
    int i = blockIdx.x * 256 + threadIdx.x;
    int h = i >> 10, k = i & 1023;
    WqaT[i] = f2bf(Wqa[k * HH + h]);
}

// ---------------- bf16 MFMA GEMM, BK=64, XOR-swizzled LDS ----------------
// C[N,1024] = A[N,1024] @ BT^T + bias
// MODE 1: write bf16 to Cb | MODE 2: write fp32 Cf = v + bf2f(res)
// LDS layout: row stride 64 elems (128 B); 16B chunk c of row r stored at
// chunk-position c ^ (r & 7)  -> fragment ds_read_b128 is exact 2-way (free).
template<int MODE>
__global__ __launch_bounds__(256)
void gemm_kernel(const u16* __restrict__ A, const u16* __restrict__ BT,
                 const float* __restrict__ bias, const u16* __restrict__ res,
                 float* __restrict__ Cf, u16* __restrict__ Cb) {
    __shared__ u16 sA[128 * 64];
    __shared__ u16 sB[128 * 64];
    const int row0 = blockIdx.x * 128;
    const int col0 = blockIdx.y * 128;
    const int t = threadIdx.x;
    const int w = t >> 6, lane = t & 63;
    const int wr = (w >> 1) * 64, wc = (w & 1) * 64;
    const int m16 = lane & 15, quad = lane >> 4;

    f32x4 acc[4][4];
    #pragma unroll
    for (int i = 0; i < 4; i++)
        #pragma unroll
        for (int j = 0; j < 4; j++)
            acc[i][j] = (f32x4){0.f, 0.f, 0.f, 0.f};

    // staging: thread t owns LDS rows (j*32 + t>>3), chunk-position t&7.
    // That position must hold global chunk (t&7) ^ ((t>>3)&7).
    const int srow = t >> 3;
    const int scol = ((t & 7) ^ (srow & 7)) * 8;
    const u16* Ag = A + (size_t)(row0 + srow) * DD + scol;
    const u16* Bg = BT + (size_t)(col0 + srow) * DD + scol;

    for (int k0 = 0; k0 < DD; k0 += 64) {
        __syncthreads();
        #pragma unroll
        for (int j = 0; j < 4; j++) {
            load_lds16(Ag + k0 + (size_t)j * 32 * DD, &sA[j * 2048 + t * 8]);
            load_lds16(Bg + k0 + (size_t)j * 32 * DD, &sB[j * 2048 + t * 8]);
        }
        __syncthreads();
        #pragma unroll
        for (int ks = 0; ks < 2; ks++) {
            const int cpos = ((ks * 4 + quad) ^ (m16 & 7)) * 8;
            bf16x8 af[4], bfr[4];
            #pragma unroll
            for (int i = 0; i < 4; i++) {
                af[i]  = *(const bf16x8*)&sA[(wr + i * 16 + m16) * 64 + cpos];
                bfr[i] = *(const bf16x8*)&sB[(wc + i * 16 + m16) * 64 + cpos];
            }
            #pragma unroll
            for (int mi = 0; mi < 4; mi++)
                #pragma unroll
                for (int ni = 0; ni < 4; ni++)
                    acc[mi][ni] = __builtin_amdgcn_mfma_f32_16x16x32_bf16(
                        af[mi], bfr[ni], acc[mi][ni], 0, 0, 0);
        }
    }

    #pragma unroll
    for (int mi = 0; mi < 4; mi++) {
        #pragma unroll
        for (int r = 0; r < 4; r++) {
            int row = row0 + wr + mi * 16 + quad * 4 + r;
            #pragma unroll
            for (int ni = 0; ni < 4; ni++) {
                int col = col0 + wc + ni * 16 + m16;
                float v = acc[mi][ni][r] + bias[col];
                size_t idx = (size_t)row * DD + col;
                if (MODE == 1) Cb[idx] = f2bf(v);
                else Cf[idx] = v + bf2f(res[idx]);
            }
        }
    }
}

// ---------------- raw qscore via MFMA, K-split 4 -> separate slices ----------------
// grid = (NROWS/64, 4). qraw[split][b][h][s] = sum_{k in split} q[s][k]*Wqa[k][h]
__global__ __launch_bounds__(256)
void qscore_mfma_kernel(const u16* __restrict__ qbf, const u16* __restrict__ WqaT,
                        float* __restrict__ qraw) {
    int w = threadIdx.x >> 6, lane = threadIdx.x & 63;
    int row0 = blockIdx.x * 64 + w * 16;
    int kbase = blockIdx.y * 256;
    int m16 = lane & 15, quad = lane >> 4;
    f32x4 acc = (f32x4){0.f, 0.f, 0.f, 0.f};
    const u16* ap = qbf + (size_t)(row0 + m16) * DD + kbase + quad * 8;
    const u16* bp = WqaT + (size_t)m16 * DD + kbase + quad * 8;
    #pragma unroll
    for (int kk = 0; kk < 256; kk += 32) {
        bf16x8 a = *(const bf16x8*)(ap + kk);
        bf16x8 b = *(const bf16x8*)(bp + kk);
        acc = __builtin_amdgcn_mfma_f32_16x16x32_bf16(a, b, acc, 0, 0, 0);
    }
    #pragma unroll
    for (int r = 0; r < 4; r++) {
        int grow = row0 + quad * 4 + r;
        int b = grow >> 11, sidx = grow & 2047;
        qraw[((size_t)(blockIdx.y * BB + b) * HH + m16) * SS + sidx] = acc[r];
    }
}

// ---------------- softmax over S, writes slice 0 ----------------
// EPI: x = sum of 4 K-split slices, then (x+bqa[h])*scale+mask
template<bool EPI>
__global__ __launch_bounds__(256)
void softmax_kernel(float* __restrict__ score, const float* __restrict__ bqa,
                    const float* __restrict__ mask) {
    int bh = blockIdx.x;
    int b = bh >> 4, h = bh & 15;
    float* srow = score + ((size_t)bh << 11);
    __shared__ float rm[4], rs[4];
    int t = threadIdx.x;

    float v[8];
    float m = -1e30f;
    #pragma unroll
    for (int i = 0; i < 8; i++) {
        int off = t + i * 256;
        float x;
        if (EPI) {
            x = srow[off] + srow[off + QSLICE] + srow[off + 2 * QSLICE] + srow[off + 3 * QSLICE];
            x = (x + bqa[h]) * 0.125f + mask[b * SS + off];
        } else {
            x = srow[off];
        }
        v[i] = x; m = fmaxf(m, x);
    }
    #pragma unroll
    for (int off = 32; off; off >>= 1) m = fmaxf(m, __shfl_xor(m, off));
    if ((t & 63) == 0) rm[t >> 6] = m;
    __syncthreads();
    m = fmaxf(fmaxf(rm[0], rm[1]), fmaxf(rm[2], rm[3]));

    float sum = 0.f;
    #pragma unroll
    for (int i = 0; i < 8; i++) { v[i] = __expf(v[i] - m); sum += v[i]; }
    #pragma unroll
    for (int off = 32; off; off >>= 1) sum += __shfl_xor(sum, off);
    if ((t & 63) == 0) rs[t >> 6] = sum;
    __syncthreads();
    float inv = 1.0f / (rs[0] + rs[1] + rs[2] + rs[3]);
    #pragma unroll
    for (int i = 0; i < 8; i++) srow[t + i * 256] = v[i] * inv;
}

// ---------------- pooled[b,:,:] += sum_{s in 32-chunk} w[b,h,s] * X[b,s,:] ----------------
// grid = (BB, SS/32). Full 2KB rows read coalesced; lane owns (h=lane>>2, 16 dims).
__global__ __launch_bounds__(256)
void pool_kernel(const float* __restrict__ w, const u16* __restrict__ X,
                 float* __restrict__ pooled) {
    int b = blockIdx.x;
    int s0 = blockIdx.y * 32;
    int t = threadIdx.x;
    int wid = t >> 6, lane = t & 63;
    int h = lane >> 2;
    __shared__ float sw[16 * 33];
    __shared__ float pr[4][64 * 17];
    {
        int hh = t >> 4, si = t & 15;
        const float* wr = w + ((size_t)(b * HH + hh) << 11) + s0;
        sw[hh * 33 + si] = wr[si];
        sw[hh * 33 + si + 16] = wr[si + 16];
    }
    __syncthreads();
    float acc[16];
    #pragma unroll
    for (int j = 0; j < 16; j++) acc[j] = 0.f;
    const u16* xbase = X + ((size_t)(b * SS + s0 + wid * 8) << 10) + lane * 16;
    #pragma unroll
    for (int rr = 0; rr < 8; rr++) {
        float ws = sw[h * 33 + wid * 8 + rr];
        const uint4* xp = (const uint4*)(xbase + (size_t)rr * DD);
        uint4 x0 = xp[0], x1 = xp[1];
        unsigned xw[8] = {x0.x, x0.y, x0.z, x0.w, x1.x, x1.y, x1.z, x1.w};
        #pragma unroll
        for (int i2 = 0; i2 < 8; i2++) {
            union { unsigned u; float f; } lo, hi;
            lo.u = xw[i2] << 16; hi.u = xw[i2] & 0xffff0000u;
            acc[2 * i2]     += ws * lo.f;
            acc[2 * i2 + 1] += ws * hi.f;
        }
    }
    #pragma unroll
    for (int j = 0; j < 16; j++) pr[wid][lane * 17 + j] = acc[j];
    __syncthreads();
    #pragma unroll
    for (int i = 0; i < 4; i++) {
        int idx = t + i * 256;                       // 0..1023 = lane'*16 + j
        int l2 = idx >> 4, j2 = idx & 15;
        float v = pr[0][l2 * 17 + j2] + pr[1][l2 * 17 + j2] +
                  pr[2][l2 * 17 + j2] + pr[3][l2 * 17 + j2];
        int od = (l2 >> 2) * 64 + (l2 & 3) * 16 + j2;  // h*64 + d
        atomicAdd(&pooled[b * DD + od], v);
    }
}

// ---------------- qk_score[b,h,s] = (k[b,s,h*64:]·pq[b,h,:])*scale + mask ----------------
__global__ __launch_bounds__(256)
void qkscore_kernel(const u16* __restrict__ kbf, const float* __restrict__ pq,
                    const float* __restrict__ mask, float* __restrict__ qkscore) {
    int row = blockIdx.x * 4 + (threadIdx.x >> 6);
    int lane = threadIdx.x & 63;
    int b = row >> 11, s = row & 2047;
    int h = lane >> 2, dp = lane & 3;
    const u16* kp = kbf + (size_t)row * DD + h * 64 + dp * 16;
    const float* pqp = pq + (size_t)(b * HH + h) * 64 + dp * 16;
    const uint4* kp4 = (const uint4*)kp;
    uint4 ka = kp4[0], kb4 = kp4[1];
    unsigned kw[8] = {ka.x, ka.y, ka.z, ka.w, kb4.x, kb4.y, kb4.z, kb4.w};
    float acc = 0.f;
    #pragma unroll
    for (int i = 0; i < 8; i++) {
        union { unsigned u; float f; } lo, hi;
        lo.u = kw[i] << 16;
        hi.u = kw[i] & 0xffff0000u;
        acc += lo.f * pqp[2 * i] + hi.f * pqp[2 * i + 1];
    }
    acc += __shfl_xor(acc, 1);
    acc += __shfl_xor(acc, 2);
    if (dp == 0) qkscore[(size_t)(b * HH + h) * SS + s] = acc * 0.125f + mask[b * SS + s];
}

// ---------------- weighted_bf[b,s,h*64+d] = bf16(pk[b,h,d]*q_bf[b,s,h*64+d]) ----------------
__global__ __launch_bounds__(256)
void weighted_kernel(const u16* __restrict__ qbf, const float* __restrict__ pk,
                     u16* __restrict__ wout) {
    int i = blockIdx.x * 256 + threadIdx.x;
    int row = i >> 8;
    int c0 = (i & 255) << 2;
    int b = row >> 11;
    int h = c0 >> 6, d = c0 & 63;
    ushort4 qv = ((const ushort4*)qbf)[i];
    const float4 pv = *(const float4*)(pk + (size_t)(b * HH + h) * 64 + d);
    ushort4 o;
    o.x = f2bf(bf2f(qv.x) * pv.x); o.y = f2bf(bf2f(qv.y) * pv.y);
    o.z = f2bf(bf2f(qv.z) * pv.z); o.w = f2bf(bf2f(qv.w) * pv.w);
    ((ushort4*)wout)[i] = o;
}

extern "C" void kernel_launch(void* const* d_in, const int* in_sizes, int n_in,
                              void* d_out, int out_size, void* d_ws, size_t ws_size,
                              hipStream_t stream) {
    const float* hs   = (const float*)d_in[0];
    const float* mask = (const float*)d_in[1];
    const float* Wq   = (const float*)d_in[2];
    const float* bq   = (const float*)d_in[3];
    const float* Wqa  = (const float*)d_in[4];
    const float* bqa  = (const float*)d_in[5];
    const float* Wk   = (const float*)d_in[6];
    const float* bk   = (const float*)d_in[7];
    const float* Wt   = (const float*)d_in[8];
    const float* bt   = (const float*)d_in[9];
    float* out = (float*)d_out;

    char* ws = (char*)d_ws;
    u16*   hs_bf = (u16*)ws;   ws += (size_t)NROWS * DD * 2;
    u16*   WqT   = (u16*)ws;   ws += (size_t)DD * DD * 2;
    u16*   WkT   = (u16*)ws;   ws += (size_t)DD * DD * 2;
    u16*   WtT   = (u16*)ws;   ws += (size_t)DD * DD * 2;
    u16*   WqaT  = (u16*)ws;   ws += (size_t)HH * DD * 2;
    u16*   q_bf  = (u16*)ws;   ws += (size_t)NROWS * DD * 2;
    u16*   k_bf  = (u16*)ws;   ws += (size_t)NROWS * DD * 2;
    float* qraw  = (float*)ws; ws += QSLICE * 4 * 4;   // 4 K-split slices
    float* qksc  = (float*)ws; ws += (size_t)BB * HH * SS * 4;
    float* pq    = (float*)ws; ws += (size_t)BB * HH * 64 * 4;
    float* pk    = (float*)ws; ws += (size_t)BB * HH * 64 * 4;
    u16*   wbf   = hs_bf;  // alias: hs_bf dead after gemm k, wbf written after

    int n4 = NROWS * DD / 4;
    cast_bf16_kernel<<<n4 / 256, 256, 0, stream>>>(hs, hs_bf, n4);
    transpose_cast_kernel<<<dim3(32, 32), 256, 0, stream>>>(Wq, WqT);
    transpose_cast_kernel<<<dim3(32, 32), 256, 0, stream>>>(Wk, WkT);
    transpose_cast_kernel<<<dim3(32, 32), 256, 0, stream>>>(Wt, WtT);
    wqa_transpose_kernel<<<HH * DD / 256, 256, 0, stream>>>(Wqa, WqaT);

    hipMemsetAsync(pq, 0, (size_t)BB * HH * 64 * 4, stream);
    hipMemsetAsync(pk, 0, (size_t)BB * HH * 64 * 4, stream);

    gemm_kernel<1><<<dim3(NROWS / 128, DD / 128), 256, 0, stream>>>(hs_bf, WqT, bq, nullptr, nullptr, q_bf);
    gemm_kernel<1><<<dim3(NROWS / 128, DD / 128), 256, 0, stream>>>(hs_bf, WkT, bk, nullptr, nullptr, k_bf);

    qscore_mfma_kernel<<<dim3(NROWS / 64, 4), 256, 0, stream>>>(q_bf, WqaT, qraw);
    softmax_kernel<true><<<BB * HH, 256, 0, stream>>>(qraw, bqa, mask);
    pool_kernel<<<dim3(BB, SS / 32), 256, 0, stream>>>(qraw, q_bf, pq);
    qkscore_kernel<<<NROWS / 4, 256, 0, stream>>>(k_bf, pq, mask, qksc);
    softmax_kernel<false><<<BB * HH, 256, 0, stream>>>(qksc, nullptr, nullptr);
    pool_kernel<<<dim3(BB, SS / 32), 256, 0, stream>>>(qksc, k_bf, pk);
    weighted_kernel<<<n4 / 256, 256, 0, stream>>>(q_bf, pk, wbf);

    gemm_kernel<2><<<dim3(NROWS / 128, DD / 128), 256, 0, stream>>>(wbf, WtT, bt, q_bf, out, nullptr);
}